// Round 10
// baseline (504.090 us; speedup 1.0000x reference)
//
#include <hip/hip_runtime.h>
#include <math.h>

#define NUM_NODES 94
#define SEQ_LEN 784
#define OUT_CLASSES 10
#define THREADS 128     // 2 waves per element

#define TWO_GAMMA 0.2f
#define OM2 0.0503551324598949f            // (2*pi/28)^2
#define INV_SQRT_N 0.103142124625879       // 1/sqrt(94)
#define LOG2E 1.4426950408889634
// exp2 arg = 2A*log2e -> fold 2*INV_SQRT_N*LOG2E into all I-path weights
#define WSCALE ((float)(2.0 * INV_SQRT_N * LOG2E))

typedef float f2 __attribute__((ext_vector_type(2)));

__device__ __forceinline__ float dpp_xor1(float x) {   // quad_perm(1,0,3,2)
    return __int_as_float(__builtin_amdgcn_mov_dpp(__float_as_int(x), 0xB1, 0xF, 0xF, true));
}
__device__ __forceinline__ float dpp_xor2(float x) {   // quad_perm(2,3,0,1)
    return __int_as_float(__builtin_amdgcn_mov_dpp(__float_as_int(x), 0x4E, 0xF, 0xF, true));
}
__device__ __forceinline__ float dpp_mir8(float x) {   // ROW_HALF_MIRROR: i<->7-i
    return __int_as_float(__builtin_amdgcn_mov_dpp(__float_as_int(x), 0x141, 0xF, 0xF, true));
}

// Element split across 2 waves (K-halves of 48 cols). W = 72 floats/lane --
// the first design whose register need (~125) fits a budget the allocator
// will grant (R8/R9: 144-float W -> 100/132 granted -> AGPR-copy tax).
// 2048 waves total = 2 waves/SIMD: co-resident waves hide LDS/dpp latency
// that was fully exposed at R9's 1 wave/SIMD.
__global__
__attribute__((amdgpu_flat_work_group_size(THREADS, THREADS), amdgpu_waves_per_eu(2, 2)))
void horn_kernel(
    const float* __restrict__ input,   // (1024, 784)
    const float* __restrict__ w_ih,    // (94, 1)
    const float* __restrict__ b_ih,    // (94)
    const float* __restrict__ w_hh,    // (94, 94)
    const float* __restrict__ b_hh,    // (94)
    const float* __restrict__ w_ro,    // (10, 94)
    const float* __restrict__ b_ro,    // (10)
    float* __restrict__ out)           // (1024, 10)
{
    __shared__ __align__(16) float ysh[2][96];      // per-WAVE full y copy
    __shared__ __align__(16) float psh[2][2][96];   // [parity][wave][row] partials

    const int tid  = threadIdx.x;
    const int wv   = tid >> 6;         // wave id 0/1 (K-half)
    const int lane = tid & 63;
    const int g    = lane >> 3;        // row-group: rows 12g..12g+11
    const int lw   = lane & 7;         // col-chunk within half: 6 cols
    const int bb   = blockIdx.x;       // batch element

    const int b0  = lane & 1, b1 = (lane >> 1) & 1, b2v = (lane >> 2) & 1;
    const bool c0 = ((b0 ^ b2v) != 0);
    const bool c1 = ((b1 ^ b2v) != 0);
    const bool c2 = (b2v != 0);

    // ---- W block: rows 12g..12g+11 x cols 48wv+6lw..+5, pre-scaled ----
    const int row0 = 12 * g;
    const int col0 = 48 * wv + 6 * lw;
    f2 w2[12][3];
    #pragma unroll
    for (int i = 0; i < 12; i++) {
        const int rr = row0 + i;
        #pragma unroll
        for (int c = 0; c < 6; c++) {
            const int cc = col0 + c;
            float v = (rr < NUM_NODES && cc < NUM_NODES)
                        ? w_hh[rr * NUM_NODES + cc] * WSCALE : 0.0f;
            w2[i][c >> 1][c & 1] = v;
        }
    }

    // Owned rows after in-wave transpose-reduce (machinery verified R6-R9):
    // nA unique per 8-lane group; nB (rows 8..11) duplicated on mir8 pairs.
    const int nA = row0 + 4 * b2v + 2 * (b1 ^ b2v) + (b0 ^ b2v);
    const int nB = row0 + 8 + 2 * (b1 ^ b2v) + (b0 ^ b2v);
    const float wihA  = (nA < NUM_NODES) ? w_ih[nA] * WSCALE : 0.0f;
    const float biasA = (nA < NUM_NODES) ? (b_ih[nA] + b_hh[nA]) * WSCALE : 0.0f;
    const float wihB  = (nB < NUM_NODES) ? w_ih[nB] * WSCALE : 0.0f;
    const float biasB = (nB < NUM_NODES) ? (b_ih[nB] + b_hh[nB]) * WSCALE : 0.0f;

    float xA = 0.0f, yA = 0.0f, xB = 0.0f, yB = 0.0f;

    // Init own y copy; barrier covers both waves' init.
    ysh[wv][nA] = 0.0f;
    ysh[wv][nB] = 0.0f;
    __syncthreads();

    const float* srow = input + (size_t)bb * SEQ_LEN;
    float sc = srow[0];                        // uniform -> scalar load

    const f2* yv = (const f2*)&ysh[wv][col0];  // 8B-aligned (col0 even)

    for (int t = 0; t < SEQ_LEN; t++) {
        const int tn = (t + 1 < SEQ_LEN) ? t + 1 : (SEQ_LEN - 1);
        float sn = srow[tn];                   // prefetch next input scalar

        // ---- read own 6-col y chunk (own-wave buffer, no barrier) ----
        f2 yy0 = yv[0], yy1 = yv[1], yy2 = yv[2];

        // ---- 12 rows x 6 cols partial dots (36 packed FMAs) ----
        f2 P[12];
        #pragma unroll
        for (int i = 0; i < 12; i++) {
            f2 p = w2[i][0] * yy0;
            p += w2[i][1] * yy1;
            p += w2[i][2] * yy2;
            P[i] = p;
        }
        float P0 = P[0][0] + P[0][1],   P1 = P[1][0] + P[1][1];
        float P2 = P[2][0] + P[2][1],   P3 = P[3][0] + P[3][1];
        float P4 = P[4][0] + P[4][1],   P5 = P[5][0] + P[5][1];
        float P6 = P[6][0] + P[6][1],   P7 = P[7][0] + P[7][1];
        float P8 = P[8][0] + P[8][1],   P9 = P[9][0] + P[9][1];
        float P10 = P[10][0] + P[10][1], P11 = P[11][0] + P[11][1];

        // ---- 8-lane transpose-reduce -> per-row K-half partials ----
        float Q0 = (c0 ? P1 : P0) + dpp_xor1(c0 ? P0 : P1);
        float Q1 = (c0 ? P3 : P2) + dpp_xor1(c0 ? P2 : P3);
        float Q2 = (c0 ? P5 : P4) + dpp_xor1(c0 ? P4 : P5);
        float Q3 = (c0 ? P7 : P6) + dpp_xor1(c0 ? P6 : P7);
        float Q4 = (c0 ? P9 : P8) + dpp_xor1(c0 ? P8 : P9);
        float Q5 = (c0 ? P11 : P10) + dpp_xor1(c0 ? P10 : P11);
        float R0 = (c1 ? Q1 : Q0) + dpp_xor2(c1 ? Q0 : Q1);
        float R1 = (c1 ? Q3 : Q2) + dpp_xor2(c1 ? Q2 : Q3);
        float R2 = (c1 ? Q5 : Q4) + dpp_xor2(c1 ? Q4 : Q5);
        float SA = (c2 ? R1 : R0) + dpp_mir8(c2 ? R0 : R1);  // row nA, half sum
        float SB = R2 + dpp_mir8(R2);                        // row nB, half sum

        // ---- cross-wave combine (parity double-buffer kills the race) ----
        const int pp = t & 1;
        psh[pp][wv][nA] = SA;
        psh[pp][wv][nB] = SB;      // pair-duplicate same value: benign
        __syncthreads();
        SA += psh[pp][wv ^ 1][nA];
        SB += psh[pp][wv ^ 1][nB];

        // ---- dynamics (duplicated in both waves -- cheaper than a 2nd barrier) ----
        float eA = __builtin_amdgcn_exp2f(fmaf(sc, wihA, biasA) + SA);
        float aA = 0.5f - __builtin_amdgcn_rcpf(eA + 1.0f);  // 0.5*tanh(A)
        aA = fmaf(-TWO_GAMMA, yA, aA);
        aA = fmaf(-OM2, xA, aA);
        xA += yA;  yA += aA;

        float eB = __builtin_amdgcn_exp2f(fmaf(sc, wihB, biasB) + SB);
        float aB = 0.5f - __builtin_amdgcn_rcpf(eB + 1.0f);
        aB = fmaf(-TWO_GAMMA, yB, aB);
        aB = fmaf(-OM2, xB, aB);
        xB += yB;  yB += aB;

        // ---- publish new y to OWN buffer (same-wave lockstep + fence) ----
        ysh[wv][nA] = yA;
        ysh[wv][nB] = yB;
        asm volatile("s_waitcnt lgkmcnt(0)" ::: "memory");

        sc = sn;
    }

    // ---- epilogue: wave 0 gathers x and projects ----
    if (wv == 0) {
        psh[0][0][nA] = xA;
        psh[0][0][nB] = xB;
    }
    asm volatile("s_waitcnt lgkmcnt(0)" ::: "memory");

    if (tid < OUT_CLASSES) {           // tid<10 -> wave 0 lanes
        float acc = b_ro[tid];
        #pragma unroll 2
        for (int j = 0; j < NUM_NODES; j++) {
            acc += psh[0][0][j] * w_ro[tid * NUM_NODES + j];
        }
        out[(size_t)bb * OUT_CLASSES + tid] = acc;
    }
}

extern "C" void kernel_launch(void* const* d_in, const int* in_sizes, int n_in,
                              void* d_out, int out_size, void* d_ws, size_t ws_size,
                              hipStream_t stream) {
    const float* input = (const float*)d_in[0];
    const float* w_ih  = (const float*)d_in[1];
    const float* b_ih  = (const float*)d_in[2];
    const float* w_hh  = (const float*)d_in[3];
    const float* b_hh  = (const float*)d_in[4];
    const float* w_ro  = (const float*)d_in[5];
    const float* b_ro  = (const float*)d_in[6];
    float* out = (float*)d_out;

    const int batch = in_sizes[0] / SEQ_LEN;   // 1024
    dim3 grid(batch);                          // 1 element per 2-wave block
    dim3 block(THREADS);

    hipLaunchKernelGGL(horn_kernel, grid, block, 0, stream,
                       input, w_ih, b_ih, w_hh, b_hh, w_ro, b_ro, out);
}

// Round 11
// 314.745 us; speedup vs baseline: 1.6016x; 1.6016x over previous
//
#include <hip/hip_runtime.h>
#include <math.h>

#define NUM_NODES 94
#define SEQ_LEN 784
#define OUT_CLASSES 10

#define TWO_GAMMA 0.2f
#define OM2 0.0503551324598949f            // (2*pi/28)^2
#define INV_SQRT_N 0.103142124625879       // 1/sqrt(94)
#define LOG2E 1.4426950408889634
// exp2 arg = 2A*log2e -> fold 2*INV_SQRT_N*LOG2E into all I-path weights
#define WSCALE ((float)(2.0 * INV_SQRT_N * LOG2E))

typedef _Float16 h2 __attribute__((ext_vector_type(2)));
typedef _Float16 h4 __attribute__((ext_vector_type(4)));

__device__ __forceinline__ float dpp_xor1(float x) {   // quad_perm(1,0,3,2)
    return __int_as_float(__builtin_amdgcn_mov_dpp(__float_as_int(x), 0xB1, 0xF, 0xF, true));
}
__device__ __forceinline__ float dpp_xor2(float x) {   // quad_perm(2,3,0,1)
    return __int_as_float(__builtin_amdgcn_mov_dpp(__float_as_int(x), 0x4E, 0xF, 0xF, true));
}
__device__ __forceinline__ float dpp_mir8(float x) {   // ROW_HALF_MIRROR: i<->i^7
    return __int_as_float(__builtin_amdgcn_mov_dpp(__float_as_int(x), 0x141, 0xF, 0xF, true));
}

__device__ __forceinline__ float dot2(h2 a, h2 b, float c) {
#if __has_builtin(__builtin_amdgcn_fdot2)
    return __builtin_amdgcn_fdot2(a, b, c, false);   // v_dot2_f32_f16
#else
    return c + (float)a[0] * (float)b[0] + (float)a[1] * (float)b[1];
#endif
}

// One element per WAVE, barrier-free (R9 skeleton, best=358us). Changes:
// (1) W as packed f16 pairs (72 regs, was 144) + y published as f16; dots
//     via v_dot2_f32_f16 with f32 accumulate -- live set ~117 regs, the
//     first design UNDER the allocator's observed grant (132), so no
//     AGPR-park / remat tax (the ~1-inst-per-FMA overhead seen R2-R10).
// (2) Select-free butterfly: the c0/c1/c2 cndmasks are folded into the
//     W row-load permutation (slot j = row 4(j2^c2)+2(j1^c1)+(j0^c0)),
//     reduce = 11 pure dpp-adds.
__global__
__attribute__((amdgpu_flat_work_group_size(64, 64), amdgpu_waves_per_eu(1, 1)))
void horn_kernel(
    const float* __restrict__ input,   // (1024, 784)
    const float* __restrict__ w_ih,    // (94, 1)
    const float* __restrict__ b_ih,    // (94)
    const float* __restrict__ w_hh,    // (94, 94)
    const float* __restrict__ b_hh,    // (94)
    const float* __restrict__ w_ro,    // (10, 94)
    const float* __restrict__ b_ro,    // (10)
    float* __restrict__ out)           // (1024, 10)
{
    __shared__ __align__(16) _Float16 ysh[96];   // y exchange (f16)
    __shared__ __align__(16) float    xsh[96];   // epilogue x gather (f32)

    const int lane = threadIdx.x;      // 0..63
    const int g    = lane >> 3;        // row-group: rows 12g..12g+11
    const int lw   = lane & 7;         // col-chunk: cols 12lw..12lw+11
    const int bb   = blockIdx.x;       // batch element

    const int b0  = lane & 1, b1 = (lane >> 1) & 1, b2v = (lane >> 2) & 1;
    const int c0i = b0 ^ b2v;
    const int c1i = b1 ^ b2v;
    const int c2i = b2v;

    const int row0 = 12 * g, col0 = 12 * lw;

    // ---- W block with folded row permutation, f16-packed, pre-scaled ----
    // Slots 0..7  (A): row = row0 + 4(j2^c2) + 2(j1^c1) + (j0^c0)
    // Slots 8..11 (B): row = row0 + 8 + 2(j1^c1) + (j0^c0)
    h2 w2[12][6];
    #pragma unroll
    for (int j = 0; j < 12; j++) {
        int rr;
        if (j < 8) {
            rr = row0 + 4 * (((j >> 2) & 1) ^ c2i)
                      + 2 * (((j >> 1) & 1) ^ c1i)
                      +     ((j & 1) ^ c0i);
        } else {
            const int jj = j - 8;
            rr = row0 + 8 + 2 * (((jj >> 1) & 1) ^ c1i)
                          +     ((jj & 1) ^ c0i);
        }
        #pragma unroll
        for (int c = 0; c < 12; c++) {
            const int cc = col0 + c;
            float v = (rr < NUM_NODES && cc < NUM_NODES)
                        ? w_hh[rr * NUM_NODES + cc] * WSCALE : 0.0f;
            w2[j][c >> 1][c & 1] = (_Float16)v;
        }
    }

    // Owned rows (unchanged from verified R6-R9 machinery):
    const int nA = row0 + 4 * c2i + 2 * c1i + c0i;
    const int nB = row0 + 8 + 2 * c1i + c0i;
    const float wihA  = (nA < NUM_NODES) ? w_ih[nA] * WSCALE : 0.0f;
    const float biasA = (nA < NUM_NODES) ? (b_ih[nA] + b_hh[nA]) * WSCALE : 0.0f;
    const float wihB  = (nB < NUM_NODES) ? w_ih[nB] * WSCALE : 0.0f;
    const float biasB = (nB < NUM_NODES) ? (b_ih[nB] + b_hh[nB]) * WSCALE : 0.0f;

    float xA = 0.0f, yA = 0.0f, xB = 0.0f, yB = 0.0f;

    // Init published y (covers all 96 slots: nA unique, nB pair-duplicated).
    ysh[nA] = (_Float16)0.0f;
    ysh[nB] = (_Float16)0.0f;
    asm volatile("s_waitcnt lgkmcnt(0)" ::: "memory");

    const float* srow = input + (size_t)bb * SEQ_LEN;
    float sc = srow[0];                        // wave-uniform -> scalar load

    const h4* yv4 = (const h4*)&ysh[col0];     // byte 24*lw: 8B-aligned

    for (int t = 0; t < SEQ_LEN; t++) {
        const int tn = (t + 1 < SEQ_LEN) ? t + 1 : (SEQ_LEN - 1);
        float sn = srow[tn];                   // prefetch next input scalar

        // ---- read own 12-col y chunk (3x ds_read_b64, bank-clean) ----
        h4 Y0 = yv4[0], Y1 = yv4[1], Y2 = yv4[2];
        h2 yy0 = __builtin_shufflevector(Y0, Y0, 0, 1);
        h2 yy1 = __builtin_shufflevector(Y0, Y0, 2, 3);
        h2 yy2 = __builtin_shufflevector(Y1, Y1, 0, 1);
        h2 yy3 = __builtin_shufflevector(Y1, Y1, 2, 3);
        h2 yy4 = __builtin_shufflevector(Y2, Y2, 0, 1);
        h2 yy5 = __builtin_shufflevector(Y2, Y2, 2, 3);

        // ---- 12 rows x 12 cols: 72 v_dot2_f32_f16 (f32 accumulate) ----
        float P[12];
        #pragma unroll
        for (int i = 0; i < 12; i++) {
            float p = dot2(w2[i][0], yy0, 0.0f);
            p = dot2(w2[i][1], yy1, p);
            p = dot2(w2[i][2], yy2, p);
            p = dot2(w2[i][3], yy3, p);
            p = dot2(w2[i][4], yy4, p);
            p = dot2(w2[i][5], yy5, p);
            P[i] = p;
        }

        // ---- select-free butterfly (row permutation folded at load) ----
        float Q0 = P[0]  + dpp_xor1(P[1]);
        float Q1 = P[2]  + dpp_xor1(P[3]);
        float Q2 = P[4]  + dpp_xor1(P[5]);
        float Q3 = P[6]  + dpp_xor1(P[7]);
        float Q4 = P[8]  + dpp_xor1(P[9]);
        float Q5 = P[10] + dpp_xor1(P[11]);
        float R0 = Q0 + dpp_xor2(Q1);
        float R1 = Q2 + dpp_xor2(Q3);
        float R2 = Q4 + dpp_xor2(Q5);
        float SA = R0 + dpp_mir8(R1);          // full dot, row nA
        float SB = R2 + dpp_mir8(R2);          // full dot, row nB

        // ---- dynamics (f32 state; padded rows see all-zero W -> stay 0) ----
        float eA = __builtin_amdgcn_exp2f(fmaf(sc, wihA, biasA) + SA);
        float aA = 0.5f - __builtin_amdgcn_rcpf(eA + 1.0f);  // 0.5*tanh(A)
        aA = fmaf(-TWO_GAMMA, yA, aA);
        aA = fmaf(-OM2, xA, aA);
        xA += yA;  yA += aA;

        float eB = __builtin_amdgcn_exp2f(fmaf(sc, wihB, biasB) + SB);
        float aB = 0.5f - __builtin_amdgcn_rcpf(eB + 1.0f);
        aB = fmaf(-TWO_GAMMA, yB, aB);
        aB = fmaf(-OM2, xB, aB);
        xB += yB;  yB += aB;

        // ---- publish new y (f16, wave-lockstep + fence; no barrier) ----
        ysh[nA] = (_Float16)yA;
        ysh[nB] = (_Float16)yB;      // pair-duplicate same value: benign
        asm volatile("s_waitcnt lgkmcnt(0)" ::: "memory");

        sc = sn;
    }

    // ---- epilogue: gather x (f32), project to classes ----
    xsh[nA] = xA;
    xsh[nB] = xB;
    asm volatile("s_waitcnt lgkmcnt(0)" ::: "memory");

    if (lane < OUT_CLASSES) {
        float acc = b_ro[lane];
        #pragma unroll 2
        for (int j = 0; j < NUM_NODES; j++) {
            acc += xsh[j] * w_ro[lane * NUM_NODES + j];
        }
        out[(size_t)bb * OUT_CLASSES + lane] = acc;
    }
}

extern "C" void kernel_launch(void* const* d_in, const int* in_sizes, int n_in,
                              void* d_out, int out_size, void* d_ws, size_t ws_size,
                              hipStream_t stream) {
    const float* input = (const float*)d_in[0];
    const float* w_ih  = (const float*)d_in[1];
    const float* b_ih  = (const float*)d_in[2];
    const float* w_hh  = (const float*)d_in[3];
    const float* b_hh  = (const float*)d_in[4];
    const float* w_ro  = (const float*)d_in[5];
    const float* b_ro  = (const float*)d_in[6];
    float* out = (float*)d_out;

    const int batch = in_sizes[0] / SEQ_LEN;   // 1024
    dim3 grid(batch);                          // 1 element per 1-wave block
    dim3 block(64);

    hipLaunchKernelGGL(horn_kernel, grid, block, 0, stream,
                       input, w_ih, b_ih, w_hh, b_hh, w_ro, b_ro, out);
}